// Round 13
// baseline (156.627 us; speedup 1.0000x reference)
//
#include <hip/hip_runtime.h>
#include <hip/hip_bf16.h>
#include <math.h>

#define NEGF (-1e30f)
#define LOG2E 1.4426950408889634f
#define LN2F 0.6931471805599453f
#define TSCALE 2.885390081777927f     // 2*log2(e), folded into f and g

typedef __attribute__((ext_vector_type(8))) short bf16x8;
typedef __attribute__((ext_vector_type(4))) float f32x4;

#define DROWS_PAD 480        // diagonals 0..459 used; padded (NCH*48 <= 480)
#define DPITCH 64
#define CH 48                // alpha chunk: 48 rows = 24 KB LDS per buffer

__device__ __forceinline__ unsigned short f2bf(float x) {
    __hip_bfloat16 h = __float2bfloat16(x);
    return *reinterpret_cast<unsigned short*>(&h);
}

__device__ __forceinline__ float wave_shr1(float x) {
    int i = __builtin_bit_cast(int, x);
    int r = __builtin_amdgcn_update_dpp(0, i, 0x138, 0xf, 0xf, true); // wf_shr:1
    return __builtin_bit_cast(float, r);
}

// ---------------------------------------------------------------------------
// Kernel 0 (pack): bf16 B-fragments for We (16384 entries), Wd (16384),
// and -2*Wp (2048, sigmoid form); plus csbp[v] = colsum(Wp)[v] + bp[v].
// ---------------------------------------------------------------------------
__global__ __launch_bounds__(256) void k_pack(const float* __restrict__ We,
                                              const float* __restrict__ Wd,
                                              const float* __restrict__ Wp,
                                              const float* __restrict__ bp,
                                              unsigned short* __restrict__ WeFrag,
                                              unsigned short* __restrict__ WdFrag,
                                              unsigned short* __restrict__ BfragP,
                                              float* __restrict__ csbp) {
    int gid = blockIdx.x * 256 + threadIdx.x;
    if (gid < 32768) {   // We / Wd
        const float* W = (gid < 16384) ? We : Wd;
        unsigned short* F = (gid < 16384) ? WeFrag : WdFrag;
        int s = gid & 16383;
        int lane = s & 63;
        int c = (s >> 6) & 7;
        int nt = s >> 9;
        int n = nt * 16 + (lane & 15);
        int kbase = c * 32 + ((lane >> 4) & 3) * 8;
        unsigned short* dst = F + (size_t)s * 8;
#pragma unroll
        for (int j = 0; j < 8; ++j) dst[j] = f2bf(W[(size_t)(kbase + j) * 512 + n]);
    } else if (gid < 34816) {            // -2*Wp: 2048 entries
        int s = gid - 32768;
        int lane = s & 63;
        int half = (s >> 6) & 1;
        int c = s >> 7;
        int n = half * 16 + (lane & 15);
        int kbase = c * 32 + (lane >> 4) * 8;
        unsigned short* dst = BfragP + (size_t)s * 8;
#pragma unroll
        for (int j = 0; j < 8; ++j) {
            float v = (n < 28) ? (-2.f * Wp[(kbase + j) * 28 + n]) : 0.f;
            dst[j] = f2bf(v);
        }
    } else if (gid < 34848) {            // csbp: 32 entries
        int v = gid - 34816;
        float s = 0.f;
        if (v < 28) {
            for (int k = 0; k < 512; ++k) s += Wp[k * 28 + v];
            s += bp[v];
        }
        csbp[v] = s;
    }
}

// ---------------------------------------------------------------------------
// Kernel 1 (MFMA projections): f = (enc@We)*TSCALE, g = (dec@Wd + bf)*TSCALE.
// (r8-verified scalar f2bf packing; cvt_pk asm broke correctness in r10.)
// ---------------------------------------------------------------------------
__global__ __launch_bounds__(256) void k_gemm(const float* __restrict__ enc,
                                              const float* __restrict__ dec,
                                              const float* __restrict__ bfv,
                                              const unsigned short* __restrict__ WeFrag,
                                              const unsigned short* __restrict__ WdFrag,
                                              float* __restrict__ f,
                                              float* __restrict__ g) {
    const int wid = blockIdx.x * 4 + threadIdx.y;
    const int lane = threadIdx.x;
    const int m16 = lane & 15;
    const int quad = lane >> 4;

    const float* A; const unsigned short* WF; float* Out; int M, rt, ct; bool isg;
    if (wid < 1600) { A = enc; WF = WeFrag; Out = f; M = 3200; rt = wid >> 3; ct = wid & 7; isg = false; }
    else { int w2 = wid - 1600; A = dec; WF = WdFrag; Out = g; M = 488; rt = w2 >> 3; ct = w2 & 7; isg = true; }

    const int row = rt * 16 + m16;
    const float* arow = A + (size_t)min(row, M - 1) * 256 + quad * 8;

    f32x4 acc[4];
#pragma unroll
    for (int i = 0; i < 4; ++i) acc[i] = (f32x4){0.f, 0.f, 0.f, 0.f};

#pragma unroll
    for (int c = 0; c < 8; ++c) {
        float4 a0 = *(const float4*)(arow + c * 32);
        float4 a1 = *(const float4*)(arow + c * 32 + 4);
        union { unsigned short s[8]; bf16x8 v; } Af;
        Af.s[0] = f2bf(a0.x); Af.s[1] = f2bf(a0.y);
        Af.s[2] = f2bf(a0.z); Af.s[3] = f2bf(a0.w);
        Af.s[4] = f2bf(a1.x); Af.s[5] = f2bf(a1.y);
        Af.s[6] = f2bf(a1.z); Af.s[7] = f2bf(a1.w);
#pragma unroll
        for (int i = 0; i < 4; ++i) {
            int nt = ct * 4 + i;
            bf16x8 Bv = *(const bf16x8*)(WF + (size_t)((nt * 8 + c) * 64 + lane) * 8);
            acc[i] = __builtin_amdgcn_mfma_f32_16x16x32_bf16(Af.v, Bv, acc[i], 0, 0, 0);
        }
    }

#pragma unroll
    for (int i = 0; i < 4; ++i) {
        int n = ct * 64 + i * 16 + m16;
        float bv = isg ? bfv[n] : 0.f;
#pragma unroll
        for (int r = 0; r < 4; ++r) {
            int ro = rt * 16 + quad * 4 + r;
            if (ro < M) Out[(size_t)ro * 512 + n] = (acc[i][r] + bv) * TSCALE;
        }
    }
}

// ---------------------------------------------------------------------------
// Kernel 2: per-cell blank/label log-probs (log2 domain).
// 16-wave (1024-thread) blocks, one u per wave: f tile staged once per 16 u
// (vs 8 in r8) -- staging traffic and barrier count halved, block count
// halved, occupancy unchanged (2 blocks/CU x 16 waves = 32 waves/CU at
// <=64 VGPR; kernel uses ~44). Per-wave math is bit-identical to r11
// (depth-2 prefetch, sigma via trans-pipe rcp).
// ---------------------------------------------------------------------------
__global__ __launch_bounds__(1024, 8) void k_cells(const float* __restrict__ f,
                                                   const float* __restrict__ g,
                                                   const unsigned short* __restrict__ Bfrag,
                                                   const float* __restrict__ csbp,
                                                   const int* __restrict__ targets,
                                                   const int* __restrict__ ilen,
                                                   const int* __restrict__ ulenp,
                                                   float2* __restrict__ pairD) {
    const int b = blockIdx.z;
    const int tlen = ilen[b];
    const int ulen = ulenp[b];
    const int t0 = blockIdx.x * 16;
    if (t0 >= tlen) return;                       // block-uniform exit
    if ((int)blockIdx.y * 16 > ulen) return;      // u-span entirely past ulen
    const int wave = threadIdx.y;
    const int lane = threadIdx.x;
    const int tid = wave * 64 + lane;

    __shared__ float fs[16 * 516];                // stride 516: b128 reads conflict-free

    {   // stage f tile (16 rows x 512), coalesced float4 -- once per 16 u
        const float4* src = (const float4*)(f + (size_t)(b * 400 + t0) * 512);
#pragma unroll
        for (int i = 0; i < 2; ++i) {
            int idx = tid + i * 1024;
            int row = idx >> 7;
            int c4 = idx & 127;
            float4 v = src[idx];
            *(float4*)&fs[row * 516 + c4 * 4] = v;
        }
    }
    __syncthreads();

    const int quad = lane >> 4;
    const int m16 = lane & 15;
    const int u_raw = blockIdx.y * 16 + wave;
    const int u = min(u_raw, 60);
    const float* fsrow = fs + m16 * 516 + quad * 8;
    const float* gu = g + (size_t)(b * 61 + u) * 512 + quad * 8;

    f32x4 acc0 = {0.f, 0.f, 0.f, 0.f};
    f32x4 acc1 = {0.f, 0.f, 0.f, 0.f};

    // depth-2 software pipeline (r8-verified): slots hold c and c+1; during
    // c, reload slot (c&1) with c+2 after moving its values to temps.
    float4 FA[2], FB[2], GA[2], GB[2];
    bf16x8 BR0[2], BR1[2];
#pragma unroll
    for (int c0 = 0; c0 < 2; ++c0) {
        FA[c0] = *(const float4*)(fsrow + c0 * 32);
        FB[c0] = *(const float4*)(fsrow + c0 * 32 + 4);
        GA[c0] = *(const float4*)(gu + c0 * 32);
        GB[c0] = *(const float4*)(gu + c0 * 32 + 4);
        BR0[c0] = *(const bf16x8*)(Bfrag + ((size_t)((c0 * 2 + 0) * 64 + lane)) * 8);
        BR1[c0] = *(const bf16x8*)(Bfrag + ((size_t)((c0 * 2 + 1) * 64 + lane)) * 8);
    }

#pragma unroll
    for (int c = 0; c < 16; ++c) {
        const int cu = c & 1;            // static after full unroll
        float4 fa = FA[cu], fb = FB[cu], ga = GA[cu], gb = GB[cu];
        bf16x8 b0 = BR0[cu], b1 = BR1[cu];
        if (c < 14) {                    // prefetch c+2 into the slot just freed
            FA[cu] = *(const float4*)(fsrow + (c + 2) * 32);
            FB[cu] = *(const float4*)(fsrow + (c + 2) * 32 + 4);
            GA[cu] = *(const float4*)(gu + (c + 2) * 32);
            GB[cu] = *(const float4*)(gu + (c + 2) * 32 + 4);
            BR0[cu] = *(const bf16x8*)(Bfrag + ((size_t)(((c + 2) * 2 + 0) * 64 + lane)) * 8);
            BR1[cu] = *(const bf16x8*)(Bfrag + ((size_t)(((c + 2) * 2 + 1) * 64 + lane)) * 8);
        }
        float4 s0 = fa + ga;                      // pk adds (pre-scaled by 2log2e)
        float4 s1 = fb + gb;
        // sigma = 1/(1+exp2(s)); rcp on the trans pipe (r11-verified)
        float4 r0, r1;
        r0.x = __builtin_amdgcn_rcpf(__builtin_amdgcn_exp2f(s0.x) + 1.f);
        r0.y = __builtin_amdgcn_rcpf(__builtin_amdgcn_exp2f(s0.y) + 1.f);
        r0.z = __builtin_amdgcn_rcpf(__builtin_amdgcn_exp2f(s0.z) + 1.f);
        r0.w = __builtin_amdgcn_rcpf(__builtin_amdgcn_exp2f(s0.w) + 1.f);
        r1.x = __builtin_amdgcn_rcpf(__builtin_amdgcn_exp2f(s1.x) + 1.f);
        r1.y = __builtin_amdgcn_rcpf(__builtin_amdgcn_exp2f(s1.y) + 1.f);
        r1.z = __builtin_amdgcn_rcpf(__builtin_amdgcn_exp2f(s1.z) + 1.f);
        r1.w = __builtin_amdgcn_rcpf(__builtin_amdgcn_exp2f(s1.w) + 1.f);
        union { unsigned short s[8]; bf16x8 v; } A;
        A.s[0] = f2bf(r0.x); A.s[1] = f2bf(r0.y);
        A.s[2] = f2bf(r0.z); A.s[3] = f2bf(r0.w);
        A.s[4] = f2bf(r1.x); A.s[5] = f2bf(r1.y);
        A.s[6] = f2bf(r1.z); A.s[7] = f2bf(r1.w);
        acc0 = __builtin_amdgcn_mfma_f32_16x16x32_bf16(A.v, b0, acc0, 0, 0, 0);
        acc1 = __builtin_amdgcn_mfma_f32_16x16x32_bf16(A.v, b1, acc1, 0, 0, 0);
    }

    // epilogue: logits l[v] = csbp[v] + acc  (acc = sum(-2Wp * sigma))
    const float cs0 = csbp[m16];
    const int n1 = 16 + m16;
    const bool n1v = (n1 < 28);
    const float cs1 = csbp[n1 & 31];
    int tv = targets[b * 60 + min(u, 59)];

    float res_blank[4], res_lab[4];
#pragma unroll
    for (int r = 0; r < 4; ++r) {
        float l0 = acc0[r] + cs0;
        float l1 = n1v ? (acc1[r] + cs1) : NEGF;
        float mx = fmaxf(l0, l1);
        mx = fmaxf(mx, __shfl_xor(mx, 1, 64));
        mx = fmaxf(mx, __shfl_xor(mx, 2, 64));
        mx = fmaxf(mx, __shfl_xor(mx, 4, 64));
        mx = fmaxf(mx, __shfl_xor(mx, 8, 64));
        float s = __builtin_amdgcn_exp2f((l0 - mx) * LOG2E) +
                  __builtin_amdgcn_exp2f((l1 - mx) * LOG2E);
        s += __shfl_xor(s, 1, 64);
        s += __shfl_xor(s, 2, 64);
        s += __shfl_xor(s, 4, 64);
        s += __shfl_xor(s, 8, 64);
        float lse = mx + __logf(s);
        int base = lane & 48;
        float labsrc = (tv < 16) ? l0 : l1;
        float labv = __shfl(labsrc, base | (tv & 15), 64);
        float blankv = __shfl(l1, base | 11, 64);   // v=27 -> half1 local 11
        res_blank[r] = (blankv - lse) * LOG2E;      // log2 domain
        res_lab[r] = (labv - lse) * LOG2E;
    }

    if (m16 == 0 && u_raw <= 60) {
        float2* Pd = pairD + (size_t)b * (DROWS_PAD * DPITCH);
#pragma unroll
        for (int r = 0; r < 4; ++r) {
            int t = t0 + quad * 4 + r;
            if (t < tlen) {
                int d = t + u;
                float2 pr;
                pr.x = res_blank[r];
                pr.y = (u <= 59) ? res_lab[r] : NEGF;
                Pd[d * DPITCH + u] = pr;
            }
        }
    }
}

// ---------------------------------------------------------------------------
// Kernel 3: anti-diagonal alpha recursion, producer-consumer (r6/r8-VERIFIED,
// absmax 0.0). Waves 1-3 stream pairD chunk k+1 (48 rows, 24 KB) into
// double-buffered LDS while wave 0 runs the verbatim r2 single-step chain
// on chunk k from LDS. Double-step (r4,r7) and in-kernel fusion (r1,r9)
// both failed twice each -- permanently abandoned.
// ---------------------------------------------------------------------------
__global__ __launch_bounds__(256) void k_alpha(const float2* __restrict__ pairD,
                                               const int* __restrict__ ilen,
                                               const int* __restrict__ ulenp,
                                               float* __restrict__ out) {
    const int b = blockIdx.x;
    const int u = threadIdx.x;
    const int w = threadIdx.y;
    const float2* Pd = pairD + (size_t)b * (DROWS_PAD * DPITCH);
    const int tl = ilen[b];
    const int ul = ulenp[b];
    const int dstar = tl - 1 + ul;
    const int NCH = (dstar + CH - 1) / CH;       // <= 10; rows < NCH*CH <= 480
    const bool uok = (u <= 60);
    const bool lok = (u >= 1 && u <= 60);

    __shared__ char lbuf[2 * CH * 512];          // 48 KiB: 2 x 48 rows x 512 B

    {   // prologue: all 4 waves copy chunk 0 into buffer 0 (1536 float4)
        const int tid = w * 64 + u;
        const float4* gs = (const float4*)Pd;
        float4* ld = (float4*)lbuf;
#pragma unroll
        for (int j = 0; j < 6; ++j) ld[tid + j * 256] = gs[tid + j * 256];
    }
    __syncthreads();

    float cur = (u == 0) ? 0.f : NEGF;
    float saved = NEGF, savedBlank = NEGF;

    for (int k = 0; k < NCH; ++k) {
        if (w > 0 && (k + 1) < NCH) {            // producers: copy chunk k+1
            const int pt = (w - 1) * 64 + u;     // 0..191
            const float4* gs = (const float4*)(Pd + (size_t)(k + 1) * CH * DPITCH);
            float4* ld = (float4*)(lbuf + ((k + 1) & 1) * (CH * 512));
#pragma unroll
            for (int j = 0; j < 8; ++j)          // 192*8 = 1536 float4
                ld[pt + j * 192] = gs[pt + j * 192];
        }
        if (w == 0) {                            // consumer: chain over chunk k
            const char* base = lbuf + (k & 1) * (CH * 512);
            const int d0 = k * CH + 1;
#pragma unroll 16
            for (int r = 0; r < CH; ++r) {
                const int d = d0 + r;
                float2 v = *(const float2*)(base + r * 512 + u * 8);
                int t = d - u;
                float bv = (t >= 1 && t <= 399 && uok) ? v.x : NEGF;
                float lvn = wave_shr1(v.y);
                float lv = (lok && t >= 0 && t <= 399) ? lvn : NEGF;
                float up = wave_shr1(cur);
                float a = cur + bv;
                float c2 = up + lv;
                float mx = fmaxf(a, c2), mn = fminf(a, c2);
                float nv = mx + __log2f(1.f + __builtin_amdgcn_exp2f(mn - mx));
                bool valid = (t >= 0 && t <= 399 && uok);
                cur = valid ? nv : cur;
                saved = (d == dstar) ? cur : saved;
                savedBlank = (d == dstar) ? v.x : savedBlank;
            }
        }
        __syncthreads();
    }
    if (w == 0 && u == ul) out[b] = -(saved + savedBlank) * LN2F;
}

// ---------------------------------------------------------------------------
extern "C" void kernel_launch(void* const* d_in, const int* in_sizes, int n_in,
                              void* d_out, int out_size, void* d_ws, size_t ws_size,
                              hipStream_t stream) {
    const float* enc = (const float*)d_in[0];
    const float* dec = (const float*)d_in[1];
    const float* We  = (const float*)d_in[2];
    const float* Wd  = (const float*)d_in[3];
    const float* bf  = (const float*)d_in[4];
    const float* Wp  = (const float*)d_in[5];
    const float* bp  = (const float*)d_in[6];
    const int* targets = (const int*)d_in[7];
    const int* ilen    = (const int*)d_in[8];
    const int* ulen    = (const int*)d_in[9];
    float* out = (float*)d_out;
    float* ws = (float*)d_ws;

    float* f     = ws;                                        // 1,638,400 f
    float* g     = ws + 1638400;                              //   249,856 f
    unsigned short* BfragP = (unsigned short*)(ws + 1888256); //  16,384 u16
    unsigned short* WeFrag = (unsigned short*)(ws + 1896448); // 131,072 u16
    unsigned short* WdFrag = (unsigned short*)(ws + 1961984); // 131,072 u16
    float* csbp  = ws + 2027520;                              //        32 f
    float2* pairD = (float2*)(ws + 2027552);                  // 8*480*64 float2

    k_pack<<<137, 256, 0, stream>>>(We, Wd, Wp, bp, WeFrag, WdFrag, BfragP, csbp);

    k_gemm<<<462, dim3(64, 4, 1), 0, stream>>>(enc, dec, bf, WeFrag, WdFrag, f, g);

    dim3 gridC(25, 4, 8);
    dim3 blockC(64, 16, 1);
    k_cells<<<gridC, blockC, 0, stream>>>(f, g, BfragP, csbp, targets, ilen, ulen, pairD);

    k_alpha<<<8, dim3(64, 4, 1), 0, stream>>>(pairD, ilen, ulen, out);
}

// Round 14
// 148.355 us; speedup vs baseline: 1.0558x; 1.0558x over previous
//
#include <hip/hip_runtime.h>
#include <hip/hip_bf16.h>
#include <math.h>

#define NEGF (-1e30f)
#define LOG2E 1.4426950408889634f
#define LN2F 0.6931471805599453f
#define TSCALE 2.885390081777927f     // 2*log2(e), folded into f and g

typedef __attribute__((ext_vector_type(8))) short bf16x8;
typedef __attribute__((ext_vector_type(4))) float f32x4;

#define DROWS_PAD 480        // diagonals 0..459 used; padded (NCH*48 <= 480)
#define DPITCH 64
#define CH 48                // alpha chunk: 48 rows = 24 KB LDS per buffer

__device__ __forceinline__ unsigned short f2bf(float x) {
    __hip_bfloat16 h = __float2bfloat16(x);
    return *reinterpret_cast<unsigned short*>(&h);
}

__device__ __forceinline__ float wave_shr1(float x) {
    int i = __builtin_bit_cast(int, x);
    int r = __builtin_amdgcn_update_dpp(0, i, 0x138, 0xf, 0xf, true); // wf_shr:1
    return __builtin_bit_cast(float, r);
}

// ---------------------------------------------------------------------------
// Kernel 0 (pack): bf16 B-fragments for We (16384 entries), Wd (16384),
// and -2*Wp (2048, sigmoid form); plus csbp[v] = colsum(Wp)[v] + bp[v].
// ---------------------------------------------------------------------------
__global__ __launch_bounds__(256) void k_pack(const float* __restrict__ We,
                                              const float* __restrict__ Wd,
                                              const float* __restrict__ Wp,
                                              const float* __restrict__ bp,
                                              unsigned short* __restrict__ WeFrag,
                                              unsigned short* __restrict__ WdFrag,
                                              unsigned short* __restrict__ BfragP,
                                              float* __restrict__ csbp) {
    int gid = blockIdx.x * 256 + threadIdx.x;
    if (gid < 32768) {   // We / Wd
        const float* W = (gid < 16384) ? We : Wd;
        unsigned short* F = (gid < 16384) ? WeFrag : WdFrag;
        int s = gid & 16383;
        int lane = s & 63;
        int c = (s >> 6) & 7;
        int nt = s >> 9;
        int n = nt * 16 + (lane & 15);
        int kbase = c * 32 + ((lane >> 4) & 3) * 8;
        unsigned short* dst = F + (size_t)s * 8;
#pragma unroll
        for (int j = 0; j < 8; ++j) dst[j] = f2bf(W[(size_t)(kbase + j) * 512 + n]);
    } else if (gid < 34816) {            // -2*Wp: 2048 entries
        int s = gid - 32768;
        int lane = s & 63;
        int half = (s >> 6) & 1;
        int c = s >> 7;
        int n = half * 16 + (lane & 15);
        int kbase = c * 32 + (lane >> 4) * 8;
        unsigned short* dst = BfragP + (size_t)s * 8;
#pragma unroll
        for (int j = 0; j < 8; ++j) {
            float v = (n < 28) ? (-2.f * Wp[(kbase + j) * 28 + n]) : 0.f;
            dst[j] = f2bf(v);
        }
    } else if (gid < 34848) {            // csbp: 32 entries
        int v = gid - 34816;
        float s = 0.f;
        if (v < 28) {
            for (int k = 0; k < 512; ++k) s += Wp[k * 28 + v];
            s += bp[v];
        }
        csbp[v] = s;
    }
}

// ---------------------------------------------------------------------------
// Kernel 1 (MFMA projections): f = (enc@We)*TSCALE, g = (dec@Wd + bf)*TSCALE.
// (r8-verified scalar f2bf packing; cvt_pk asm broke correctness in r10.)
// ---------------------------------------------------------------------------
__global__ __launch_bounds__(256) void k_gemm(const float* __restrict__ enc,
                                              const float* __restrict__ dec,
                                              const float* __restrict__ bfv,
                                              const unsigned short* __restrict__ WeFrag,
                                              const unsigned short* __restrict__ WdFrag,
                                              float* __restrict__ f,
                                              float* __restrict__ g) {
    const int wid = blockIdx.x * 4 + threadIdx.y;
    const int lane = threadIdx.x;
    const int m16 = lane & 15;
    const int quad = lane >> 4;

    const float* A; const unsigned short* WF; float* Out; int M, rt, ct; bool isg;
    if (wid < 1600) { A = enc; WF = WeFrag; Out = f; M = 3200; rt = wid >> 3; ct = wid & 7; isg = false; }
    else { int w2 = wid - 1600; A = dec; WF = WdFrag; Out = g; M = 488; rt = w2 >> 3; ct = w2 & 7; isg = true; }

    const int row = rt * 16 + m16;
    const float* arow = A + (size_t)min(row, M - 1) * 256 + quad * 8;

    f32x4 acc[4];
#pragma unroll
    for (int i = 0; i < 4; ++i) acc[i] = (f32x4){0.f, 0.f, 0.f, 0.f};

#pragma unroll
    for (int c = 0; c < 8; ++c) {
        float4 a0 = *(const float4*)(arow + c * 32);
        float4 a1 = *(const float4*)(arow + c * 32 + 4);
        union { unsigned short s[8]; bf16x8 v; } Af;
        Af.s[0] = f2bf(a0.x); Af.s[1] = f2bf(a0.y);
        Af.s[2] = f2bf(a0.z); Af.s[3] = f2bf(a0.w);
        Af.s[4] = f2bf(a1.x); Af.s[5] = f2bf(a1.y);
        Af.s[6] = f2bf(a1.z); Af.s[7] = f2bf(a1.w);
#pragma unroll
        for (int i = 0; i < 4; ++i) {
            int nt = ct * 4 + i;
            bf16x8 Bv = *(const bf16x8*)(WF + (size_t)((nt * 8 + c) * 64 + lane) * 8);
            acc[i] = __builtin_amdgcn_mfma_f32_16x16x32_bf16(Af.v, Bv, acc[i], 0, 0, 0);
        }
    }

#pragma unroll
    for (int i = 0; i < 4; ++i) {
        int n = ct * 64 + i * 16 + m16;
        float bv = isg ? bfv[n] : 0.f;
#pragma unroll
        for (int r = 0; r < 4; ++r) {
            int ro = rt * 16 + quad * 4 + r;
            if (ro < M) Out[(size_t)ro * 512 + n] = (acc[i][r] + bv) * TSCALE;
        }
    }
}

// ---------------------------------------------------------------------------
// Kernel 2: per-cell blank/label log-probs (log2 domain).
// 16-wave (1024-thread) blocks, one u per wave: f tile staged once per 16 u.
// __launch_bounds__(1024, 4): VGPR cap 128 (r13's (1024,8) capped at 64 ->
// compiler clamped to 32 VGPR, dismantled the depth-2 pipeline, 3x slower
// -- same trap as r2). Occupancy: 2 blocks/CU x 16 waves = 32 waves/CU,
// same as r11. Per-wave math bit-identical to r11.
// ---------------------------------------------------------------------------
__global__ __launch_bounds__(1024, 4) void k_cells(const float* __restrict__ f,
                                                   const float* __restrict__ g,
                                                   const unsigned short* __restrict__ Bfrag,
                                                   const float* __restrict__ csbp,
                                                   const int* __restrict__ targets,
                                                   const int* __restrict__ ilen,
                                                   const int* __restrict__ ulenp,
                                                   float2* __restrict__ pairD) {
    const int b = blockIdx.z;
    const int tlen = ilen[b];
    const int ulen = ulenp[b];
    const int t0 = blockIdx.x * 16;
    if (t0 >= tlen) return;                       // block-uniform exit
    if ((int)blockIdx.y * 16 > ulen) return;      // u-span entirely past ulen
    const int wave = threadIdx.y;
    const int lane = threadIdx.x;
    const int tid = wave * 64 + lane;

    __shared__ float fs[16 * 516];                // stride 516: b128 reads conflict-free

    {   // stage f tile (16 rows x 512), coalesced float4 -- once per 16 u
        const float4* src = (const float4*)(f + (size_t)(b * 400 + t0) * 512);
#pragma unroll
        for (int i = 0; i < 2; ++i) {
            int idx = tid + i * 1024;
            int row = idx >> 7;
            int c4 = idx & 127;
            float4 v = src[idx];
            *(float4*)&fs[row * 516 + c4 * 4] = v;
        }
    }
    __syncthreads();

    const int quad = lane >> 4;
    const int m16 = lane & 15;
    const int u_raw = blockIdx.y * 16 + wave;
    const int u = min(u_raw, 60);
    const float* fsrow = fs + m16 * 516 + quad * 8;
    const float* gu = g + (size_t)(b * 61 + u) * 512 + quad * 8;

    f32x4 acc0 = {0.f, 0.f, 0.f, 0.f};
    f32x4 acc1 = {0.f, 0.f, 0.f, 0.f};

    // depth-2 software pipeline (r8-verified): slots hold c and c+1; during
    // c, reload slot (c&1) with c+2 after moving its values to temps.
    float4 FA[2], FB[2], GA[2], GB[2];
    bf16x8 BR0[2], BR1[2];
#pragma unroll
    for (int c0 = 0; c0 < 2; ++c0) {
        FA[c0] = *(const float4*)(fsrow + c0 * 32);
        FB[c0] = *(const float4*)(fsrow + c0 * 32 + 4);
        GA[c0] = *(const float4*)(gu + c0 * 32);
        GB[c0] = *(const float4*)(gu + c0 * 32 + 4);
        BR0[c0] = *(const bf16x8*)(Bfrag + ((size_t)((c0 * 2 + 0) * 64 + lane)) * 8);
        BR1[c0] = *(const bf16x8*)(Bfrag + ((size_t)((c0 * 2 + 1) * 64 + lane)) * 8);
    }

#pragma unroll
    for (int c = 0; c < 16; ++c) {
        const int cu = c & 1;            // static after full unroll
        float4 fa = FA[cu], fb = FB[cu], ga = GA[cu], gb = GB[cu];
        bf16x8 b0 = BR0[cu], b1 = BR1[cu];
        if (c < 14) {                    // prefetch c+2 into the slot just freed
            FA[cu] = *(const float4*)(fsrow + (c + 2) * 32);
            FB[cu] = *(const float4*)(fsrow + (c + 2) * 32 + 4);
            GA[cu] = *(const float4*)(gu + (c + 2) * 32);
            GB[cu] = *(const float4*)(gu + (c + 2) * 32 + 4);
            BR0[cu] = *(const bf16x8*)(Bfrag + ((size_t)(((c + 2) * 2 + 0) * 64 + lane)) * 8);
            BR1[cu] = *(const bf16x8*)(Bfrag + ((size_t)(((c + 2) * 2 + 1) * 64 + lane)) * 8);
        }
        float4 s0 = fa + ga;                      // pk adds (pre-scaled by 2log2e)
        float4 s1 = fb + gb;
        // sigma = 1/(1+exp2(s)); rcp on the trans pipe (r11-verified)
        float4 r0, r1;
        r0.x = __builtin_amdgcn_rcpf(__builtin_amdgcn_exp2f(s0.x) + 1.f);
        r0.y = __builtin_amdgcn_rcpf(__builtin_amdgcn_exp2f(s0.y) + 1.f);
        r0.z = __builtin_amdgcn_rcpf(__builtin_amdgcn_exp2f(s0.z) + 1.f);
        r0.w = __builtin_amdgcn_rcpf(__builtin_amdgcn_exp2f(s0.w) + 1.f);
        r1.x = __builtin_amdgcn_rcpf(__builtin_amdgcn_exp2f(s1.x) + 1.f);
        r1.y = __builtin_amdgcn_rcpf(__builtin_amdgcn_exp2f(s1.y) + 1.f);
        r1.z = __builtin_amdgcn_rcpf(__builtin_amdgcn_exp2f(s1.z) + 1.f);
        r1.w = __builtin_amdgcn_rcpf(__builtin_amdgcn_exp2f(s1.w) + 1.f);
        union { unsigned short s[8]; bf16x8 v; } A;
        A.s[0] = f2bf(r0.x); A.s[1] = f2bf(r0.y);
        A.s[2] = f2bf(r0.z); A.s[3] = f2bf(r0.w);
        A.s[4] = f2bf(r1.x); A.s[5] = f2bf(r1.y);
        A.s[6] = f2bf(r1.z); A.s[7] = f2bf(r1.w);
        acc0 = __builtin_amdgcn_mfma_f32_16x16x32_bf16(A.v, b0, acc0, 0, 0, 0);
        acc1 = __builtin_amdgcn_mfma_f32_16x16x32_bf16(A.v, b1, acc1, 0, 0, 0);
    }

    // epilogue: logits l[v] = csbp[v] + acc  (acc = sum(-2Wp * sigma))
    const float cs0 = csbp[m16];
    const int n1 = 16 + m16;
    const bool n1v = (n1 < 28);
    const float cs1 = csbp[n1 & 31];
    int tv = targets[b * 60 + min(u, 59)];

    float res_blank[4], res_lab[4];
#pragma unroll
    for (int r = 0; r < 4; ++r) {
        float l0 = acc0[r] + cs0;
        float l1 = n1v ? (acc1[r] + cs1) : NEGF;
        float mx = fmaxf(l0, l1);
        mx = fmaxf(mx, __shfl_xor(mx, 1, 64));
        mx = fmaxf(mx, __shfl_xor(mx, 2, 64));
        mx = fmaxf(mx, __shfl_xor(mx, 4, 64));
        mx = fmaxf(mx, __shfl_xor(mx, 8, 64));
        float s = __builtin_amdgcn_exp2f((l0 - mx) * LOG2E) +
                  __builtin_amdgcn_exp2f((l1 - mx) * LOG2E);
        s += __shfl_xor(s, 1, 64);
        s += __shfl_xor(s, 2, 64);
        s += __shfl_xor(s, 4, 64);
        s += __shfl_xor(s, 8, 64);
        float lse = mx + __logf(s);
        int base = lane & 48;
        float labsrc = (tv < 16) ? l0 : l1;
        float labv = __shfl(labsrc, base | (tv & 15), 64);
        float blankv = __shfl(l1, base | 11, 64);   // v=27 -> half1 local 11
        res_blank[r] = (blankv - lse) * LOG2E;      // log2 domain
        res_lab[r] = (labv - lse) * LOG2E;
    }

    if (m16 == 0 && u_raw <= 60) {
        float2* Pd = pairD + (size_t)b * (DROWS_PAD * DPITCH);
#pragma unroll
        for (int r = 0; r < 4; ++r) {
            int t = t0 + quad * 4 + r;
            if (t < tlen) {
                int d = t + u;
                float2 pr;
                pr.x = res_blank[r];
                pr.y = (u <= 59) ? res_lab[r] : NEGF;
                Pd[d * DPITCH + u] = pr;
            }
        }
    }
}

// ---------------------------------------------------------------------------
// Kernel 3: anti-diagonal alpha recursion, producer-consumer (r6/r8-VERIFIED,
// absmax 0.0). Waves 1-3 stream pairD chunk k+1 (48 rows, 24 KB) into
// double-buffered LDS while wave 0 runs the verbatim r2 single-step chain
// on chunk k from LDS. Double-step (r4,r7) and in-kernel fusion (r1,r9)
// both failed twice each -- permanently abandoned.
// ---------------------------------------------------------------------------
__global__ __launch_bounds__(256) void k_alpha(const float2* __restrict__ pairD,
                                               const int* __restrict__ ilen,
                                               const int* __restrict__ ulenp,
                                               float* __restrict__ out) {
    const int b = blockIdx.x;
    const int u = threadIdx.x;
    const int w = threadIdx.y;
    const float2* Pd = pairD + (size_t)b * (DROWS_PAD * DPITCH);
    const int tl = ilen[b];
    const int ul = ulenp[b];
    const int dstar = tl - 1 + ul;
    const int NCH = (dstar + CH - 1) / CH;       // <= 10; rows < NCH*CH <= 480
    const bool uok = (u <= 60);
    const bool lok = (u >= 1 && u <= 60);

    __shared__ char lbuf[2 * CH * 512];          // 48 KiB: 2 x 48 rows x 512 B

    {   // prologue: all 4 waves copy chunk 0 into buffer 0 (1536 float4)
        const int tid = w * 64 + u;
        const float4* gs = (const float4*)Pd;
        float4* ld = (float4*)lbuf;
#pragma unroll
        for (int j = 0; j < 6; ++j) ld[tid + j * 256] = gs[tid + j * 256];
    }
    __syncthreads();

    float cur = (u == 0) ? 0.f : NEGF;
    float saved = NEGF, savedBlank = NEGF;

    for (int k = 0; k < NCH; ++k) {
        if (w > 0 && (k + 1) < NCH) {            // producers: copy chunk k+1
            const int pt = (w - 1) * 64 + u;     // 0..191
            const float4* gs = (const float4*)(Pd + (size_t)(k + 1) * CH * DPITCH);
            float4* ld = (float4*)(lbuf + ((k + 1) & 1) * (CH * 512));
#pragma unroll
            for (int j = 0; j < 8; ++j)          // 192*8 = 1536 float4
                ld[pt + j * 192] = gs[pt + j * 192];
        }
        if (w == 0) {                            // consumer: chain over chunk k
            const char* base = lbuf + (k & 1) * (CH * 512);
            const int d0 = k * CH + 1;
#pragma unroll 16
            for (int r = 0; r < CH; ++r) {
                const int d = d0 + r;
                float2 v = *(const float2*)(base + r * 512 + u * 8);
                int t = d - u;
                float bv = (t >= 1 && t <= 399 && uok) ? v.x : NEGF;
                float lvn = wave_shr1(v.y);
                float lv = (lok && t >= 0 && t <= 399) ? lvn : NEGF;
                float up = wave_shr1(cur);
                float a = cur + bv;
                float c2 = up + lv;
                float mx = fmaxf(a, c2), mn = fminf(a, c2);
                float nv = mx + __log2f(1.f + __builtin_amdgcn_exp2f(mn - mx));
                bool valid = (t >= 0 && t <= 399 && uok);
                cur = valid ? nv : cur;
                saved = (d == dstar) ? cur : saved;
                savedBlank = (d == dstar) ? v.x : savedBlank;
            }
        }
        __syncthreads();
    }
    if (w == 0 && u == ul) out[b] = -(saved + savedBlank) * LN2F;
}

// ---------------------------------------------------------------------------
extern "C" void kernel_launch(void* const* d_in, const int* in_sizes, int n_in,
                              void* d_out, int out_size, void* d_ws, size_t ws_size,
                              hipStream_t stream) {
    const float* enc = (const float*)d_in[0];
    const float* dec = (const float*)d_in[1];
    const float* We  = (const float*)d_in[2];
    const float* Wd  = (const float*)d_in[3];
    const float* bf  = (const float*)d_in[4];
    const float* Wp  = (const float*)d_in[5];
    const float* bp  = (const float*)d_in[6];
    const int* targets = (const int*)d_in[7];
    const int* ilen    = (const int*)d_in[8];
    const int* ulen    = (const int*)d_in[9];
    float* out = (float*)d_out;
    float* ws = (float*)d_ws;

    float* f     = ws;                                        // 1,638,400 f
    float* g     = ws + 1638400;                              //   249,856 f
    unsigned short* BfragP = (unsigned short*)(ws + 1888256); //  16,384 u16
    unsigned short* WeFrag = (unsigned short*)(ws + 1896448); // 131,072 u16
    unsigned short* WdFrag = (unsigned short*)(ws + 1961984); // 131,072 u16
    float* csbp  = ws + 2027520;                              //        32 f
    float2* pairD = (float2*)(ws + 2027552);                  // 8*480*64 float2

    k_pack<<<137, 256, 0, stream>>>(We, Wd, Wp, bp, WeFrag, WdFrag, BfragP, csbp);

    k_gemm<<<462, dim3(64, 4, 1), 0, stream>>>(enc, dec, bf, WeFrag, WdFrag, f, g);

    dim3 gridC(25, 4, 8);
    dim3 blockC(64, 16, 1);
    k_cells<<<gridC, blockC, 0, stream>>>(f, g, BfragP, csbp, targets, ilen, ulen, pairD);

    k_alpha<<<8, dim3(64, 4, 1), 0, stream>>>(pairD, ilen, ulen, out);
}

// Round 15
// 142.195 us; speedup vs baseline: 1.1015x; 1.0433x over previous
//
#include <hip/hip_runtime.h>
#include <hip/hip_bf16.h>
#include <math.h>

#define NEGF (-1e30f)
#define LOG2E 1.4426950408889634f
#define LN2F 0.6931471805599453f
#define TSCALE 2.885390081777927f     // 2*log2(e), folded into f and g

typedef __attribute__((ext_vector_type(8))) short bf16x8;
typedef __attribute__((ext_vector_type(4))) float f32x4;

#define DROWS_PAD 480        // diagonals 0..459 used; padded (NCH*48 <= 480)
#define DPITCH 64
#define CH 48                // alpha chunk: 48 rows = 24 KB LDS per buffer

__device__ __forceinline__ unsigned short f2bf(float x) {
    __hip_bfloat16 h = __float2bfloat16(x);
    return *reinterpret_cast<unsigned short*>(&h);
}

__device__ __forceinline__ float wave_shr1(float x) {
    int i = __builtin_bit_cast(int, x);
    int r = __builtin_amdgcn_update_dpp(0, i, 0x138, 0xf, 0xf, true); // wf_shr:1
    return __builtin_bit_cast(float, r);
}

// ---------------------------------------------------------------------------
// Kernel 0 (pack): bf16 B-fragments for We (16384 entries), Wd (16384),
// and -2*Wp (2048, sigmoid form); plus csbp[v] = colsum(Wp)[v] + bp[v].
// ---------------------------------------------------------------------------
__global__ __launch_bounds__(256) void k_pack(const float* __restrict__ We,
                                              const float* __restrict__ Wd,
                                              const float* __restrict__ Wp,
                                              const float* __restrict__ bp,
                                              unsigned short* __restrict__ WeFrag,
                                              unsigned short* __restrict__ WdFrag,
                                              unsigned short* __restrict__ BfragP,
                                              float* __restrict__ csbp) {
    int gid = blockIdx.x * 256 + threadIdx.x;
    if (gid < 32768) {   // We / Wd
        const float* W = (gid < 16384) ? We : Wd;
        unsigned short* F = (gid < 16384) ? WeFrag : WdFrag;
        int s = gid & 16383;
        int lane = s & 63;
        int c = (s >> 6) & 7;
        int nt = s >> 9;
        int n = nt * 16 + (lane & 15);
        int kbase = c * 32 + ((lane >> 4) & 3) * 8;
        unsigned short* dst = F + (size_t)s * 8;
#pragma unroll
        for (int j = 0; j < 8; ++j) dst[j] = f2bf(W[(size_t)(kbase + j) * 512 + n]);
    } else if (gid < 34816) {            // -2*Wp: 2048 entries
        int s = gid - 32768;
        int lane = s & 63;
        int half = (s >> 6) & 1;
        int c = s >> 7;
        int n = half * 16 + (lane & 15);
        int kbase = c * 32 + (lane >> 4) * 8;
        unsigned short* dst = BfragP + (size_t)s * 8;
#pragma unroll
        for (int j = 0; j < 8; ++j) {
            float v = (n < 28) ? (-2.f * Wp[(kbase + j) * 28 + n]) : 0.f;
            dst[j] = f2bf(v);
        }
    } else if (gid < 34848) {            // csbp: 32 entries
        int v = gid - 34816;
        float s = 0.f;
        if (v < 28) {
            for (int k = 0; k < 512; ++k) s += Wp[k * 28 + v];
            s += bp[v];
        }
        csbp[v] = s;
    }
}

// ---------------------------------------------------------------------------
// Kernel 1 (MFMA projections): f = (enc@We)*TSCALE, g = (dec@Wd + bf)*TSCALE.
// (r8-verified scalar f2bf packing; cvt_pk asm broke correctness in r10.)
// ---------------------------------------------------------------------------
__global__ __launch_bounds__(256) void k_gemm(const float* __restrict__ enc,
                                              const float* __restrict__ dec,
                                              const float* __restrict__ bfv,
                                              const unsigned short* __restrict__ WeFrag,
                                              const unsigned short* __restrict__ WdFrag,
                                              float* __restrict__ f,
                                              float* __restrict__ g) {
    const int wid = blockIdx.x * 4 + threadIdx.y;
    const int lane = threadIdx.x;
    const int m16 = lane & 15;
    const int quad = lane >> 4;

    const float* A; const unsigned short* WF; float* Out; int M, rt, ct; bool isg;
    if (wid < 1600) { A = enc; WF = WeFrag; Out = f; M = 3200; rt = wid >> 3; ct = wid & 7; isg = false; }
    else { int w2 = wid - 1600; A = dec; WF = WdFrag; Out = g; M = 488; rt = w2 >> 3; ct = w2 & 7; isg = true; }

    const int row = rt * 16 + m16;
    const float* arow = A + (size_t)min(row, M - 1) * 256 + quad * 8;

    f32x4 acc[4];
#pragma unroll
    for (int i = 0; i < 4; ++i) acc[i] = (f32x4){0.f, 0.f, 0.f, 0.f};

#pragma unroll
    for (int c = 0; c < 8; ++c) {
        float4 a0 = *(const float4*)(arow + c * 32);
        float4 a1 = *(const float4*)(arow + c * 32 + 4);
        union { unsigned short s[8]; bf16x8 v; } Af;
        Af.s[0] = f2bf(a0.x); Af.s[1] = f2bf(a0.y);
        Af.s[2] = f2bf(a0.z); Af.s[3] = f2bf(a0.w);
        Af.s[4] = f2bf(a1.x); Af.s[5] = f2bf(a1.y);
        Af.s[6] = f2bf(a1.z); Af.s[7] = f2bf(a1.w);
#pragma unroll
        for (int i = 0; i < 4; ++i) {
            int nt = ct * 4 + i;
            bf16x8 Bv = *(const bf16x8*)(WF + (size_t)((nt * 8 + c) * 64 + lane) * 8);
            acc[i] = __builtin_amdgcn_mfma_f32_16x16x32_bf16(Af.v, Bv, acc[i], 0, 0, 0);
        }
    }

#pragma unroll
    for (int i = 0; i < 4; ++i) {
        int n = ct * 64 + i * 16 + m16;
        float bv = isg ? bfv[n] : 0.f;
#pragma unroll
        for (int r = 0; r < 4; ++r) {
            int ro = rt * 16 + quad * 4 + r;
            if (ro < M) Out[(size_t)ro * 512 + n] = (acc[i][r] + bv) * TSCALE;
        }
    }
}

// ---------------------------------------------------------------------------
// Kernel 2: per-cell blank/label log-probs (log2 domain).
// r11-VERIFIED FINAL: 8-wave (512-thread) blocks, one u per wave, f tile
// staged once per 8 u, depth-2 register prefetch, sigma via trans-pipe rcp.
// Block-shape family swept: 4-wave u-span (r5, -8), 8-wave (r6/r8/r11,
// best), 16-wave (r13 VGPR-clamped -14; r14 with headroom -5.5). 8-wave
// balances staging reuse against barrier width and block-count tail.
// ---------------------------------------------------------------------------
__global__ __launch_bounds__(512, 4) void k_cells(const float* __restrict__ f,
                                                  const float* __restrict__ g,
                                                  const unsigned short* __restrict__ Bfrag,
                                                  const float* __restrict__ csbp,
                                                  const int* __restrict__ targets,
                                                  const int* __restrict__ ilen,
                                                  const int* __restrict__ ulenp,
                                                  float2* __restrict__ pairD) {
    const int b = blockIdx.z;
    const int tlen = ilen[b];
    const int ulen = ulenp[b];
    const int t0 = blockIdx.x * 16;
    if (t0 >= tlen) return;                       // block-uniform exit
    if ((int)blockIdx.y * 8 > ulen) return;       // u-oct entirely past ulen
    const int wave = threadIdx.y;
    const int lane = threadIdx.x;
    const int tid = wave * 64 + lane;

    __shared__ float fs[16 * 516];                // stride 516: b128 reads conflict-free

    {   // stage f tile (16 rows x 512), coalesced float4 -- once per 8 u
        const float4* src = (const float4*)(f + (size_t)(b * 400 + t0) * 512);
#pragma unroll
        for (int i = 0; i < 4; ++i) {
            int idx = tid + i * 512;
            int row = idx >> 7;
            int c4 = idx & 127;
            float4 v = src[idx];
            *(float4*)&fs[row * 516 + c4 * 4] = v;
        }
    }
    __syncthreads();

    const int quad = lane >> 4;
    const int m16 = lane & 15;
    const int u_raw = blockIdx.y * 8 + wave;
    const int u = min(u_raw, 60);
    const float* fsrow = fs + m16 * 516 + quad * 8;
    const float* gu = g + (size_t)(b * 61 + u) * 512 + quad * 8;

    f32x4 acc0 = {0.f, 0.f, 0.f, 0.f};
    f32x4 acc1 = {0.f, 0.f, 0.f, 0.f};

    // depth-2 software pipeline (r8-verified): slots hold c and c+1; during
    // c, reload slot (c&1) with c+2 after moving its values to temps.
    float4 FA[2], FB[2], GA[2], GB[2];
    bf16x8 BR0[2], BR1[2];
#pragma unroll
    for (int c0 = 0; c0 < 2; ++c0) {
        FA[c0] = *(const float4*)(fsrow + c0 * 32);
        FB[c0] = *(const float4*)(fsrow + c0 * 32 + 4);
        GA[c0] = *(const float4*)(gu + c0 * 32);
        GB[c0] = *(const float4*)(gu + c0 * 32 + 4);
        BR0[c0] = *(const bf16x8*)(Bfrag + ((size_t)((c0 * 2 + 0) * 64 + lane)) * 8);
        BR1[c0] = *(const bf16x8*)(Bfrag + ((size_t)((c0 * 2 + 1) * 64 + lane)) * 8);
    }

#pragma unroll
    for (int c = 0; c < 16; ++c) {
        const int cu = c & 1;            // static after full unroll
        float4 fa = FA[cu], fb = FB[cu], ga = GA[cu], gb = GB[cu];
        bf16x8 b0 = BR0[cu], b1 = BR1[cu];
        if (c < 14) {                    // prefetch c+2 into the slot just freed
            FA[cu] = *(const float4*)(fsrow + (c + 2) * 32);
            FB[cu] = *(const float4*)(fsrow + (c + 2) * 32 + 4);
            GA[cu] = *(const float4*)(gu + (c + 2) * 32);
            GB[cu] = *(const float4*)(gu + (c + 2) * 32 + 4);
            BR0[cu] = *(const bf16x8*)(Bfrag + ((size_t)(((c + 2) * 2 + 0) * 64 + lane)) * 8);
            BR1[cu] = *(const bf16x8*)(Bfrag + ((size_t)(((c + 2) * 2 + 1) * 64 + lane)) * 8);
        }
        float4 s0 = fa + ga;                      // pk adds (pre-scaled by 2log2e)
        float4 s1 = fb + gb;
        // sigma = 1/(1+exp2(s)); rcp on the trans pipe (r11-verified)
        float4 r0, r1;
        r0.x = __builtin_amdgcn_rcpf(__builtin_amdgcn_exp2f(s0.x) + 1.f);
        r0.y = __builtin_amdgcn_rcpf(__builtin_amdgcn_exp2f(s0.y) + 1.f);
        r0.z = __builtin_amdgcn_rcpf(__builtin_amdgcn_exp2f(s0.z) + 1.f);
        r0.w = __builtin_amdgcn_rcpf(__builtin_amdgcn_exp2f(s0.w) + 1.f);
        r1.x = __builtin_amdgcn_rcpf(__builtin_amdgcn_exp2f(s1.x) + 1.f);
        r1.y = __builtin_amdgcn_rcpf(__builtin_amdgcn_exp2f(s1.y) + 1.f);
        r1.z = __builtin_amdgcn_rcpf(__builtin_amdgcn_exp2f(s1.z) + 1.f);
        r1.w = __builtin_amdgcn_rcpf(__builtin_amdgcn_exp2f(s1.w) + 1.f);
        union { unsigned short s[8]; bf16x8 v; } A;
        A.s[0] = f2bf(r0.x); A.s[1] = f2bf(r0.y);
        A.s[2] = f2bf(r0.z); A.s[3] = f2bf(r0.w);
        A.s[4] = f2bf(r1.x); A.s[5] = f2bf(r1.y);
        A.s[6] = f2bf(r1.z); A.s[7] = f2bf(r1.w);
        acc0 = __builtin_amdgcn_mfma_f32_16x16x32_bf16(A.v, b0, acc0, 0, 0, 0);
        acc1 = __builtin_amdgcn_mfma_f32_16x16x32_bf16(A.v, b1, acc1, 0, 0, 0);
    }

    // epilogue: logits l[v] = csbp[v] + acc  (acc = sum(-2Wp * sigma))
    const float cs0 = csbp[m16];
    const int n1 = 16 + m16;
    const bool n1v = (n1 < 28);
    const float cs1 = csbp[n1 & 31];
    int tv = targets[b * 60 + min(u, 59)];

    float res_blank[4], res_lab[4];
#pragma unroll
    for (int r = 0; r < 4; ++r) {
        float l0 = acc0[r] + cs0;
        float l1 = n1v ? (acc1[r] + cs1) : NEGF;
        float mx = fmaxf(l0, l1);
        mx = fmaxf(mx, __shfl_xor(mx, 1, 64));
        mx = fmaxf(mx, __shfl_xor(mx, 2, 64));
        mx = fmaxf(mx, __shfl_xor(mx, 4, 64));
        mx = fmaxf(mx, __shfl_xor(mx, 8, 64));
        float s = __builtin_amdgcn_exp2f((l0 - mx) * LOG2E) +
                  __builtin_amdgcn_exp2f((l1 - mx) * LOG2E);
        s += __shfl_xor(s, 1, 64);
        s += __shfl_xor(s, 2, 64);
        s += __shfl_xor(s, 4, 64);
        s += __shfl_xor(s, 8, 64);
        float lse = mx + __logf(s);
        int base = lane & 48;
        float labsrc = (tv < 16) ? l0 : l1;
        float labv = __shfl(labsrc, base | (tv & 15), 64);
        float blankv = __shfl(l1, base | 11, 64);   // v=27 -> half1 local 11
        res_blank[r] = (blankv - lse) * LOG2E;      // log2 domain
        res_lab[r] = (labv - lse) * LOG2E;
    }

    if (m16 == 0 && u_raw <= 60) {
        float2* Pd = pairD + (size_t)b * (DROWS_PAD * DPITCH);
#pragma unroll
        for (int r = 0; r < 4; ++r) {
            int t = t0 + quad * 4 + r;
            if (t < tlen) {
                int d = t + u;
                float2 pr;
                pr.x = res_blank[r];
                pr.y = (u <= 59) ? res_lab[r] : NEGF;
                Pd[d * DPITCH + u] = pr;
            }
        }
    }
}

// ---------------------------------------------------------------------------
// Kernel 3: anti-diagonal alpha recursion, producer-consumer (r6/r8-VERIFIED,
// absmax 0.0). Waves 1-3 stream pairD chunk k+1 (48 rows, 24 KB) into
// double-buffered LDS while wave 0 runs the verbatim r2 single-step chain
// on chunk k from LDS. Double-step (r4,r7) and in-kernel fusion (r1,r9)
// both failed twice each -- permanently abandoned.
// ---------------------------------------------------------------------------
__global__ __launch_bounds__(256) void k_alpha(const float2* __restrict__ pairD,
                                               const int* __restrict__ ilen,
                                               const int* __restrict__ ulenp,
                                               float* __restrict__ out) {
    const int b = blockIdx.x;
    const int u = threadIdx.x;
    const int w = threadIdx.y;
    const float2* Pd = pairD + (size_t)b * (DROWS_PAD * DPITCH);
    const int tl = ilen[b];
    const int ul = ulenp[b];
    const int dstar = tl - 1 + ul;
    const int NCH = (dstar + CH - 1) / CH;       // <= 10; rows < NCH*CH <= 480
    const bool uok = (u <= 60);
    const bool lok = (u >= 1 && u <= 60);

    __shared__ char lbuf[2 * CH * 512];          // 48 KiB: 2 x 48 rows x 512 B

    {   // prologue: all 4 waves copy chunk 0 into buffer 0 (1536 float4)
        const int tid = w * 64 + u;
        const float4* gs = (const float4*)Pd;
        float4* ld = (float4*)lbuf;
#pragma unroll
        for (int j = 0; j < 6; ++j) ld[tid + j * 256] = gs[tid + j * 256];
    }
    __syncthreads();

    float cur = (u == 0) ? 0.f : NEGF;
    float saved = NEGF, savedBlank = NEGF;

    for (int k = 0; k < NCH; ++k) {
        if (w > 0 && (k + 1) < NCH) {            // producers: copy chunk k+1
            const int pt = (w - 1) * 64 + u;     // 0..191
            const float4* gs = (const float4*)(Pd + (size_t)(k + 1) * CH * DPITCH);
            float4* ld = (float4*)(lbuf + ((k + 1) & 1) * (CH * 512));
#pragma unroll
            for (int j = 0; j < 8; ++j)          // 192*8 = 1536 float4
                ld[pt + j * 192] = gs[pt + j * 192];
        }
        if (w == 0) {                            // consumer: chain over chunk k
            const char* base = lbuf + (k & 1) * (CH * 512);
            const int d0 = k * CH + 1;
#pragma unroll 16
            for (int r = 0; r < CH; ++r) {
                const int d = d0 + r;
                float2 v = *(const float2*)(base + r * 512 + u * 8);
                int t = d - u;
                float bv = (t >= 1 && t <= 399 && uok) ? v.x : NEGF;
                float lvn = wave_shr1(v.y);
                float lv = (lok && t >= 0 && t <= 399) ? lvn : NEGF;
                float up = wave_shr1(cur);
                float a = cur + bv;
                float c2 = up + lv;
                float mx = fmaxf(a, c2), mn = fminf(a, c2);
                float nv = mx + __log2f(1.f + __builtin_amdgcn_exp2f(mn - mx));
                bool valid = (t >= 0 && t <= 399 && uok);
                cur = valid ? nv : cur;
                saved = (d == dstar) ? cur : saved;
                savedBlank = (d == dstar) ? v.x : savedBlank;
            }
        }
        __syncthreads();
    }
    if (w == 0 && u == ul) out[b] = -(saved + savedBlank) * LN2F;
}

// ---------------------------------------------------------------------------
extern "C" void kernel_launch(void* const* d_in, const int* in_sizes, int n_in,
                              void* d_out, int out_size, void* d_ws, size_t ws_size,
                              hipStream_t stream) {
    const float* enc = (const float*)d_in[0];
    const float* dec = (const float*)d_in[1];
    const float* We  = (const float*)d_in[2];
    const float* Wd  = (const float*)d_in[3];
    const float* bf  = (const float*)d_in[4];
    const float* Wp  = (const float*)d_in[5];
    const float* bp  = (const float*)d_in[6];
    const int* targets = (const int*)d_in[7];
    const int* ilen    = (const int*)d_in[8];
    const int* ulen    = (const int*)d_in[9];
    float* out = (float*)d_out;
    float* ws = (float*)d_ws;

    float* f     = ws;                                        // 1,638,400 f
    float* g     = ws + 1638400;                              //   249,856 f
    unsigned short* BfragP = (unsigned short*)(ws + 1888256); //  16,384 u16
    unsigned short* WeFrag = (unsigned short*)(ws + 1896448); // 131,072 u16
    unsigned short* WdFrag = (unsigned short*)(ws + 1961984); // 131,072 u16
    float* csbp  = ws + 2027520;                              //        32 f
    float2* pairD = (float2*)(ws + 2027552);                  // 8*480*64 float2

    k_pack<<<137, 256, 0, stream>>>(We, Wd, Wp, bp, WeFrag, WdFrag, BfragP, csbp);

    k_gemm<<<462, dim3(64, 4, 1), 0, stream>>>(enc, dec, bf, WeFrag, WdFrag, f, g);

    dim3 gridC(25, 8, 8);
    dim3 blockC(64, 8, 1);
    k_cells<<<gridC, blockC, 0, stream>>>(f, g, BfragP, csbp, targets, ilen, ulen, pairD);

    k_alpha<<<8, dim3(64, 4, 1), 0, stream>>>(pairD, ilen, ulen, out);
}